// Round 4
// baseline (5647.518 us; speedup 1.0000x reference)
//
#include <hip/hip_runtime.h>
#include <hip/hip_bf16.h>

#define BB 512
#define TT 128
#define EE 64
#define HH 512
#define VV 100
#define NG 2048

typedef __attribute__((ext_vector_type(8))) short bf16x8;
typedef __attribute__((ext_vector_type(4))) float f32x4;

__device__ __forceinline__ float sigm(float x) { return 1.f / (1.f + expf(-x)); }
__device__ __forceinline__ float bf2f(unsigned short u) {
  return __uint_as_float(((unsigned)u) << 16);
}
__device__ __forceinline__ unsigned short f2bf(float x) {  // RNE
  unsigned u = __float_as_uint(x);
  return (unsigned short)((u + 0x7fffu + ((u >> 16) & 1u)) >> 16);
}
__device__ __forceinline__ void gl16(void* lds, const void* g) {
  __builtin_amdgcn_global_load_lds((const __attribute__((address_space(1))) void*)g,
                                   (__attribute__((address_space(3))) void*)lds, 16, 0, 0);
}

// -------- precompute: P_vocab[v][n] = sum_e emb[v,e] * W0[e, n] --------
__global__ __launch_bounds__(256) void pv_kernel(
    const float* __restrict__ cemb, const float* __restrict__ W0,
    float* __restrict__ Pvocab) {
  int idx = blockIdx.x * 256 + threadIdx.x;
  if (idx >= VV * NG) return;
  int v = idx >> 11, n = idx & (NG - 1);
  float acc = 0.f;
  for (int e = 0; e < EE; e++) acc += cemb[v * EE + e] * W0[e * NG + n];
  Pvocab[idx] = acc;
}

// -------- precompute: P_state[b][n] = b0[n] + sum_k state[b,k] * W0[64+k, n] --------
__global__ __launch_bounds__(256) void ps_kernel(
    const float* __restrict__ state, const float* __restrict__ W0,
    const float* __restrict__ b0v, float* __restrict__ Pstate) {
  const int nb = blockIdx.x & 7;
  const int bb0 = (blockIdx.x >> 3) * 16;
  const int tid = threadIdx.x;
  const int n = nb * 256 + tid;
  __shared__ float Slds[16][64];
  float acc[16];
  float bv = b0v[n];
  for (int i = 0; i < 16; i++) acc[i] = bv;
  for (int kc = 0; kc < HH; kc += 64) {
    __syncthreads();
    for (int i = 0; i < 4; i++) {
      int idx = tid + 256 * i;
      int r = idx >> 6, kk = idx & 63;
      Slds[r][kk] = state[(bb0 + r) * HH + kc + kk];
    }
    __syncthreads();
    for (int kk = 0; kk < 64; kk++) {
      float w = W0[(EE + kc + kk) * NG + n];
      for (int i = 0; i < 16; i++) acc[i] += Slds[i][kk] * w;
    }
  }
  for (int i = 0; i < 16; i++) Pstate[(bb0 + i) * NG + n] = acc[i];
}

// -------- weight convert to fragment-order bf16 hi/lo --------
// Wf layout: [ntile 16][kc nkch][hl 2][ni 8][lane 64][j 8]  (chunk = 8192 shorts)
// frag-col mapping: col = ntile*32 + (ni>>2)*16 + c15 + (ni&3)*HH   (gate = ni&3)
__global__ __launch_bounds__(256) void wconv_kernel(
    const float* __restrict__ W, int koff, unsigned short* __restrict__ Wf,
    int nkch) {
  int u = blockIdx.x * 256 + threadIdx.x;
  int j = u & 7;
  int lane = (u >> 3) & 63;
  int ni = (u >> 9) & 7;
  int kc = (u >> 12) & (nkch - 1);
  int ntile = (u >> 12) / nkch;
  if (ntile >= 16) return;  // defensive
  int q = lane >> 4, c15 = lane & 15;
  int k = kc * 32 + q * 8 + j;
  int col = ntile * 32 + (ni >> 2) * 16 + c15 + (ni & 3) * HH;
  float x = W[(size_t)(koff + k) * NG + col];
  unsigned short hi = f2bf(x);
  unsigned short lo = f2bf(x - bf2f(hi));
  size_t base = ((size_t)(ntile * nkch + kc)) * 8192 + ni * 512 + lane * 8 + j;
  Wf[base] = hi;
  Wf[base + 4096] = lo;
}

// -------- Wp convert: Wpf [kc 16][hl 2][ni 8][lane 64][8], col = ni*16+c15 (pad >=VV with 0)
__global__ __launch_bounds__(256) void wconvp_kernel(
    const float* __restrict__ Wp, unsigned short* __restrict__ Wpf) {
  int u = blockIdx.x * 256 + threadIdx.x;  // 16*4096
  int j = u & 7;
  int lane = (u >> 3) & 63;
  int ni = (u >> 9) & 7;
  int kc = (u >> 12) & 15;
  int q = lane >> 4, c15 = lane & 15;
  int col = ni * 16 + c15;
  int k = kc * 32 + q * 8 + j;
  float x = (col < VV) ? Wp[(size_t)k * VV + col] : 0.f;
  unsigned short hi = f2bf(x);
  unsigned short lo = f2bf(x - bf2f(hi));
  size_t base = (size_t)kc * 8192 + ni * 512 + lane * 8 + j;
  Wpf[base] = hi;
  Wpf[base + 4096] = lo;
}

// -------- phase kernel --------
// phase p: part0 = layer0 step t=p; part1 = layer1 step t=p-1
// block: 128 threads = 2 waves; tile 64 rows x 128 gate-cols (32 cells x 4 gates)
// wave wN owns ni {4wN..4wN+3} = 16 cells x 4 gates -> gates thread-local (gate = ni&3)
// LDS reads/chunk: A 8x2 + B 16x1 = 32 b128 (N-split replication)
// h layout: [buf 2][mb 8][kch 16][hl 2][mfrag 4][lane 64][j 8]
// outsF layout: [btile 1024][kch 16][mfrag 4][lane 64][j 8] (bf16, A-frag order for proj)
__global__ __launch_bounds__(128) void phase_kernel(
    int p, const int* __restrict__ tok, const int* __restrict__ lens,
    const float* __restrict__ Pstate, const float* __restrict__ Pvocab,
    const unsigned short* __restrict__ W0f, const unsigned short* __restrict__ W1f,
    const float* __restrict__ b1,
    unsigned short* __restrict__ h0f, unsigned short* __restrict__ h1f,
    float* __restrict__ c0, float* __restrict__ c1,
    unsigned short* __restrict__ outsF) {
  const int part = blockIdx.x >> 7;
  const int t = part ? (p - 1) : p;
  if (t < 0 || t >= TT) return;
  const int bid = blockIdx.x & 127;
  // XCD-aware: bid%8 selects ntile pair -> weight slice L2-resident per XCD
  const int x = bid & 7, r = bid >> 3;
  const int mb = r & 7;                // 64-row group
  const int ntile = x * 2 + (r >> 3);  // 0..15 (32 cells)
  const int tid = threadIdx.x;
  const int wN = tid >> 6;             // 0..1 column-half
  const int lane = tid & 63;
  const int c15 = lane & 15, q = lane >> 4;

  const int wr = p & 1, rd = wr ^ 1;
  const unsigned short* h0rd = h0f + (size_t)rd * 524288;
  const unsigned short* h1rd = h1f + (size_t)rd * 524288;
  unsigned short* h0wr = h0f + (size_t)wr * 524288;
  unsigned short* h1wr = h1f + (size_t)wr * 524288;

  __shared__ __align__(16) unsigned short ldsA[2 * 4096];  // [buf][hl2][m4][lane][8]
  __shared__ __align__(16) unsigned short ldsB[2 * 8192];  // [buf][hl2][ni8][lane][8]

  f32x4 acc[4][4];  // [mfrag][gate]
  if (part == 0) {
#pragma unroll
    for (int m = 0; m < 4; m++) {
#pragma unroll
      for (int i = 0; i < 4; i++) {
        int row = mb * 64 + m * 16 + q * 4 + i;
        int tk = tok[row * TT + t];
        const float* ps = Pstate + (size_t)row * NG;
        const float* pv = Pvocab + (size_t)tk * NG;
#pragma unroll
        for (int g = 0; g < 4; g++) {
          int col = ntile * 32 + wN * 16 + c15 + g * HH;
          acc[m][g][i] = ps[col] + pv[col];
        }
      }
    }
  } else {
#pragma unroll
    for (int g = 0; g < 4; g++) {
      int col = ntile * 32 + wN * 16 + c15 + g * HH;
      float bv = b1[col];
#pragma unroll
      for (int m = 0; m < 4; m++)
#pragma unroll
        for (int i = 0; i < 4; i++) acc[m][g][i] = bv;
    }
  }

  const int nk = part ? 32 : 16;
  const unsigned short* Wsrc = part ? (W1f + (size_t)ntile * 32 * 8192)
                                    : (W0f + (size_t)ntile * 16 * 8192);

  auto stageK = [&](int kc, int buf) {
    const unsigned short* wg = Wsrc + (size_t)kc * 8192;
#pragma unroll
    for (int i2 = 0; i2 < 8; i2++) {
      int f = wN * 8 + i2;  // 0..15 = hl*8 + ni
      gl16(&ldsB[buf * 8192 + f * 512 + lane * 8], wg + f * 512 + lane * 8);
    }
    const unsigned short* asrc;
    if (part == 0) asrc = h0rd + (size_t)(mb * 16 + kc) * 4096;
    else asrc = (kc < 16) ? (h0rd + (size_t)(mb * 16 + kc) * 4096)
                          : (h1rd + (size_t)(mb * 16 + kc - 16) * 4096);
#pragma unroll
    for (int i2 = 0; i2 < 4; i2++) {
      int f = wN * 4 + i2;  // 0..7 = hl*4 + mfrag
      gl16(&ldsA[buf * 4096 + f * 512 + lane * 8], asrc + f * 512 + lane * 8);
    }
  };

  stageK(0, 0);
  __syncthreads();
  for (int kc = 0; kc < nk; kc++) {
    const int buf = kc & 1;
    if (kc + 1 < nk) stageK(kc + 1, buf ^ 1);
    bf16x8 ahi[4], alo[4];
#pragma unroll
    for (int m = 0; m < 4; m++) {
      ahi[m] = *(const bf16x8*)&ldsA[buf * 4096 + m * 512 + lane * 8];
      alo[m] = *(const bf16x8*)&ldsA[buf * 4096 + 2048 + m * 512 + lane * 8];
    }
#pragma unroll
    for (int g = 0; g < 4; g++) {
      int ni = wN * 4 + g;
      bf16x8 bhi = *(const bf16x8*)&ldsB[buf * 8192 + ni * 512 + lane * 8];
      bf16x8 blo = *(const bf16x8*)&ldsB[buf * 8192 + 4096 + ni * 512 + lane * 8];
#pragma unroll
      for (int m = 0; m < 4; m++) {
        acc[m][g] = __builtin_amdgcn_mfma_f32_16x16x32_bf16(ahi[m], bhi, acc[m][g], 0, 0, 0);
        acc[m][g] = __builtin_amdgcn_mfma_f32_16x16x32_bf16(ahi[m], blo, acc[m][g], 0, 0, 0);
        acc[m][g] = __builtin_amdgcn_mfma_f32_16x16x32_bf16(alo[m], bhi, acc[m][g], 0, 0, 0);
      }
    }
    __syncthreads();
  }

  // epilogue: thread owns cell = ntile*32 + wN*16 + c15, rows m*16+q*4+i
  float* cbuf = part ? c1 : c0;
  const unsigned short* hrd = part ? h1rd : h0rd;
  unsigned short* hwr = part ? h1wr : h0wr;
  const int cell = ntile * 32 + wN * 16 + c15;
  const int kq = wN * 2 + (c15 >> 3);
  const int jj = c15 & 7;
  const size_t hbase = (size_t)(mb * 16 + ntile) * 4096;
#pragma unroll
  for (int m = 0; m < 4; m++) {
#pragma unroll
    for (int i = 0; i < 4; i++) {
      int row = mb * 64 + m * 16 + q * 4 + i;
      bool msk = t < lens[row];
      float ig = acc[m][0][i], jg = acc[m][1][i];
      float fg = acc[m][2][i], og = acc[m][3][i];
      size_t sidx = (size_t)row * HH + cell;
      size_t hb = hbase + (size_t)m * 512 +
                  (size_t)((q * 4 + i) | (kq << 4)) * 8 + jj;
      unsigned short hh, hl_;
      if (msk) {
        float cp = cbuf[sidx];
        float nc = cp * sigm(fg + 1.f) + sigm(ig) * tanhf(jg);
        float nh = tanhf(nc) * sigm(og);
        cbuf[sidx] = nc;
        hh = f2bf(nh);
        hl_ = f2bf(nh - bf2f(hh));
      } else {
        hh = hrd[hb];
        hl_ = hrd[hb + 2048];
      }
      hwr[hb] = hh;
      hwr[hb + 2048] = hl_;
      if (part) {
        size_t oidx = (size_t)(row * 2 + (t >> 6)) * 32768 + (size_t)ntile * 2048 +
                      (size_t)((t >> 4) & 3) * 512 +
                      (size_t)((t & 15) | (kq << 4)) * 8 + jj;
        outsF[oidx] = msk ? hh : (unsigned short)0;
      }
    }
  }
}

// -------- projection via MFMA: out[bt, v] = bp[v] + outs[bt,:] @ Wp --------
// block: 128 thr / 2 waves, tile = 64 BT-rows (one btile) x 128 cols (100 valid)
__global__ __launch_bounds__(128) void proj_kernel(
    const unsigned short* __restrict__ outsF, const unsigned short* __restrict__ Wpf,
    const float* __restrict__ bp, float* __restrict__ out) {
  const int btile = blockIdx.x;  // 1024
  const int tid = threadIdx.x;
  const int wN = tid >> 6;
  const int lane = tid & 63;
  const int c15 = lane & 15, q = lane >> 4;

  __shared__ __align__(16) unsigned short ldsA[2 * 2048];  // [buf][m4][lane][8]
  __shared__ __align__(16) unsigned short ldsB[2 * 8192];  // [buf][hl2][ni8][lane][8]

  f32x4 acc[4][4];
#pragma unroll
  for (int m = 0; m < 4; m++)
#pragma unroll
    for (int g = 0; g < 4; g++)
#pragma unroll
      for (int i = 0; i < 4; i++) acc[m][g][i] = 0.f;

  const unsigned short* asrcb = outsF + (size_t)btile * 32768;

  auto stageK = [&](int kc, int buf) {
#pragma unroll
    for (int i2 = 0; i2 < 8; i2++) {
      int f = wN * 8 + i2;
      gl16(&ldsB[buf * 8192 + f * 512 + lane * 8],
           Wpf + (size_t)kc * 8192 + f * 512 + lane * 8);
    }
#pragma unroll
    for (int i2 = 0; i2 < 2; i2++) {
      int f = wN * 2 + i2;
      gl16(&ldsA[buf * 2048 + f * 512 + lane * 8],
           asrcb + (size_t)kc * 2048 + f * 512 + lane * 8);
    }
  };

  stageK(0, 0);
  __syncthreads();
  for (int kc = 0; kc < 16; kc++) {
    const int buf = kc & 1;
    if (kc + 1 < 16) stageK(kc + 1, buf ^ 1);
    bf16x8 a[4];
#pragma unroll
    for (int m = 0; m < 4; m++)
      a[m] = *(const bf16x8*)&ldsA[buf * 2048 + m * 512 + lane * 8];
#pragma unroll
    for (int g = 0; g < 4; g++) {
      int ni = wN * 4 + g;
      bf16x8 bhi = *(const bf16x8*)&ldsB[buf * 8192 + ni * 512 + lane * 8];
      bf16x8 blo = *(const bf16x8*)&ldsB[buf * 8192 + 4096 + ni * 512 + lane * 8];
#pragma unroll
      for (int m = 0; m < 4; m++) {
        acc[m][g] = __builtin_amdgcn_mfma_f32_16x16x32_bf16(a[m], bhi, acc[m][g], 0, 0, 0);
        acc[m][g] = __builtin_amdgcn_mfma_f32_16x16x32_bf16(a[m], blo, acc[m][g], 0, 0, 0);
      }
    }
    __syncthreads();
  }

#pragma unroll
  for (int g = 0; g < 4; g++) {
    int col = (wN * 4 + g) * 16 + c15;
    if (col < VV) {
      float bpv = bp[col];
#pragma unroll
      for (int m = 0; m < 4; m++)
#pragma unroll
        for (int i = 0; i < 4; i++) {
          int rowBT = btile * 64 + m * 16 + q * 4 + i;
          out[(size_t)rowBT * VV + col] = acc[m][g][i] + bpv;
        }
    }
  }
}

extern "C" void kernel_launch(void* const* d_in, const int* in_sizes, int n_in,
                              void* d_out, int out_size, void* d_ws, size_t ws_size,
                              hipStream_t stream) {
  const int* tok = (const int*)d_in[0];
  const int* lens = (const int*)d_in[1];
  const float* state = (const float*)d_in[2];
  const float* cemb = (const float*)d_in[3];
  const float* W0 = (const float*)d_in[4];
  const float* b0 = (const float*)d_in[5];
  const float* W1 = (const float*)d_in[6];
  const float* b1 = (const float*)d_in[7];
  const float* Wp = (const float*)d_in[8];
  const float* bp = (const float*)d_in[9];
  float* out = (float*)d_out;

  char* wsp = (char*)d_ws;
  float* Pstate = (float*)wsp; wsp += (size_t)BB * NG * 4;                        // 4 MB
  float* Pvocab = (float*)wsp; wsp += (size_t)VV * NG * 4;                        // 800 KB
  unsigned short* W0f = (unsigned short*)wsp; wsp += (size_t)16 * 16 * 8192 * 2;  // 4 MB
  unsigned short* W1f = (unsigned short*)wsp; wsp += (size_t)16 * 32 * 8192 * 2;  // 8 MB
  unsigned short* Wpf = (unsigned short*)wsp; wsp += (size_t)16 * 8192 * 2;       // 256 KB
  unsigned short* h0f = (unsigned short*)wsp; wsp += (size_t)2 * 524288 * 2;      // 2 MB
  unsigned short* h1f = (unsigned short*)wsp; wsp += (size_t)2 * 524288 * 2;      // 2 MB
  float* c0 = (float*)wsp; wsp += (size_t)BB * HH * 4;                            // 1 MB
  float* c1 = (float*)wsp; wsp += (size_t)BB * HH * 4;                            // 1 MB
  unsigned short* outsF = (unsigned short*)wsp;                                   // 64 MB

  // zero h0f,h1f,c0,c1 (contiguous 6 MB)
  hipMemsetAsync(h0f, 0, (size_t)2 * 2097152 + (size_t)2 * 1048576, stream);

  pv_kernel<<<(VV * NG + 255) / 256, 256, 0, stream>>>(cemb, W0, Pvocab);
  ps_kernel<<<256, 256, 0, stream>>>(state, W0, b0, Pstate);
  wconv_kernel<<<(16 * 16 * 4096) / 256, 256, 0, stream>>>(W0, EE + HH, W0f, 16);
  wconv_kernel<<<(16 * 32 * 4096) / 256, 256, 0, stream>>>(W1, 0, W1f, 32);
  wconvp_kernel<<<(16 * 4096) / 256, 256, 0, stream>>>(Wp, Wpf);

  for (int p = 0; p <= TT; p++) {
    phase_kernel<<<256, 128, 0, stream>>>(p, tok, lens, Pstate, Pvocab, W0f, W1f,
                                          b1, h0f, h1f, c0, c1, outsF);
  }

  proj_kernel<<<BB * TT / 64, 128, 0, stream>>>(outsF, Wpf, bp, out);
}